// Round 7
// baseline (204.424 us; speedup 1.0000x reference)
//
#include <hip/hip_runtime.h>
#include <math.h>
#include <stdint.h>

// ---------------------------------------------------------------------------
// v10: k_zF split into two LDS-free streaming kernels:
//   k_z: one thread per (po,p) -> z[2560][715] float2 in global (14.6 MB).
//   k_F: v7 lmin-switch chain-sum reading z from global (bit-identical math),
//        no LDS / no barriers / no duplicated z-phase; r split 4-ways.
// k_gemm2 reverted to v7 unsplit form (v9 split was neutral-negative).
// Trig table for A-pack kept from v9 (harmless).
// Pipeline: setup_w -> setup_const -> fhat -> z -> F -> gemm2.
// ---------------------------------------------------------------------------

typedef _Float16 half8 __attribute__((ext_vector_type(8)));
typedef float    f32x4 __attribute__((ext_vector_type(4)));

// workspace float offsets
#define WS_W    128     // gW [k60][sm55]                 3300
#define WS_Y    17760   // gyhat [o5][s100][i2] float2
#define WS_EM   19776   // gEm [m10][j60] float2
#define WS_TRIG 20992   // 20 dbl sin + 20 dbl cos (ex-gRT region)
#define WS_PACK 21184   // gPack[715] int
#define WS_AP   21952   // A-pack 172032 fp16
#define WS_FH   107968  // gfhat [b512][sm55][i2] float2 = 112640 floats
#define WS_DT   220608  // gDT [p715][k20] = 14300 floats
#define WS_F    234908  // gF 9,830,400 dwords (39.3 MB) B-frag layout
#define WS_Z    10100000 // gZ [po2560][p715] float2 = 3,660,800 floats (past gF end)

// setup idx ranges (non-overlapping)
#define IX_Y0    3300
#define IX_EM0   4300
#define IX_RT0   4900
#define IX_PACK0 5090
#define IX_AP0   5805
#define IX_DT0   177837   // IX_AP0 + 172032
#define N_SETUP  192137   // + 14300

__device__ __forceinline__ double ipow_d(double x, int e) {
    double r = 1.0;
    for (int i = 0; i < e; ++i) r *= x;
    return r;
}

__device__ double dsmall(int l, int mp, int m, double beta) {
    double fact[20];
    fact[0] = 1.0;
    for (int i = 1; i < 20; ++i) fact[i] = fact[i - 1] * (double)i;
    double cb = cos(0.5 * beta), sb = sin(0.5 * beta);
    double pref = sqrt(fact[l + m] * fact[l - m] * fact[l + mp] * fact[l - mp]);
    int s0 = m - mp; if (s0 < 0) s0 = 0;
    int s1 = l + m;  if (l - mp < s1) s1 = l - mp;
    double tot = 0.0;
    for (int s = s0; s <= s1; ++s) {
        double den = fact[l + m - s] * fact[s] * fact[mp - m + s] * fact[l - mp - s];
        double sgn = ((mp - m + s) & 1) ? -1.0 : 1.0;
        tot += sgn / den * ipow_d(cb, 2 * l + m - mp - 2 * s) * ipow_d(sb, mp - m + 2 * s);
    }
    return pref * tot;
}

extern "C" __global__ void k_setup_w(float* wsf) {
    double* w = (double*)wsf;
    int t = threadIdx.x;
    if (t < 60) {
        double beta = M_PI * (2 * t + 1) / 120.0;
        double sum = 0.0;
        for (int k = 0; k < 30; ++k)
            sum += sin((double)((2 * t + 1) * (2 * k + 1)) * M_PI / 120.0) / (double)(2 * k + 1);
        w[t] = (2.0 / 30.0) * sin(beta) * sum;
    }
    if (t < 20) {   // A-pack trig table: sin/cos(pi*t/10), exact same expr as original
        double ang = M_PI * (double)t / 10.0;
        ((double*)(wsf + WS_TRIG))[t]      = sin(ang);
        ((double*)(wsf + WS_TRIG))[20 + t] = cos(ang);
    }
}

extern "C" __global__ void k_setup_const(float* wsf, const float* __restrict__ kern) {
    const double* w = (const double*)wsf;
    const int tri[11] = {0, 1, 3, 6, 10, 15, 21, 28, 36, 45, 55};
    int idx = blockIdx.x * 64 + threadIdx.x;
    if (idx < IX_Y0) {                      // gW [k][sm]
        int k = idx / 55, smi = idx % 55;
        int l = 0; while (smi >= tri[l + 1]) ++l;
        int m = smi - tri[l];
        double beta = M_PI * (2 * k + 1) / 120.0;
        wsf[WS_W + idx] = (float)(w[k] * dsmall(l, m, 0, beta));
    } else if (idx < IX_EM0) {              // gyhat [o][s][i]
        int i3 = idx - IX_Y0;
        int o = i3 / 200, r5 = i3 % 200;
        int s = r5 / 2, i = r5 % 2;
        int l = 0; while ((l + 1) * (l + 1) <= s) ++l;
        int n = s - l * l - l;
        double dv = dsmall(l, n, 0, M_PI / 160.0);
        const double SC = 1.0 / sqrt(6.0 * 2.0 * 10000.0 / 900.0);
        double ar = 0.0, ai = 0.0;
        for (int g = 0; g < 6; ++g) {
            double kv = (double)kern[i * 30 + o * 6 + g];
            double ang = (double)n * M_PI * (double)g / 3.0;
            ar += kv * cos(ang);
            ai -= kv * sin(ang);
        }
        ((float2*)(wsf + WS_Y))[i3] = make_float2((float)(SC * dv * ar), (float)(SC * dv * ai));
    } else if (idx < IX_EM0 + 600) {        // gEm [m][j]
        int t = idx - IX_EM0; int m = t / 60, j = t % 60;
        double a = 2.0 * M_PI * (double)(m * j) / 60.0;
        ((float2*)(wsf + WS_EM))[t] = make_float2((float)cos(a), (float)(-sin(a)));
    } else if (idx < IX_PACK0) {
        // ex-gRT region now holds the trig table (written by k_setup_w)
    } else if (idx < IX_AP0) {              // gPack[715]
        int p = idx - IX_PACK0;
        int l = 0, bcur = 0;
        for (;;) { int bs = (l + 1) * (2 * l + 1); if (p < bcur + bs) break; bcur += bs; ++l; }
        int r = p - bcur; int L = 2 * l + 1;
        int m = r / L; int n = r % L - l;
        int smi = tri[l] + m; int sf = l * l + l + n;
        ((int*)(wsf + WS_PACK))[p] = smi * 128 + sf;
    } else if (idx < IX_DT0) {              // A-pack (A-fragment lane order), table lookup
        int ap = idx - IX_AP0;
        int j = ap & 7, lane = (ap >> 3) & 63, tc = ap >> 9;
        int t = tc % 28, c = tc / 28;
        int pq = t * 16 + (lane & 15);
        int kidx = c * 32 + ((lane >> 4) << 3) + j;
        double val = 0.0;
        if (pq < 400 && kidx < 380) {
            int r = kidx >> 1, cpart = kidx & 1;
            int m = r / 19, nn = r % 19, n = nn - 9;
            int p = pq / 20, q = pq % 20;
            int th = ((m * p + n * q) % 20 + 20) % 20;
            double wm = m ? 2.0 : 1.0;
            const double* st = (const double*)(wsf + WS_TRIG);
            val = cpart ? (-wm * st[th]) : (wm * st[20 + th]);
        }
        ((_Float16*)(wsf + WS_AP))[ap] = (_Float16)val;
    } else if (idx < N_SETUP) {             // gDT [p][k] transposed
        int i6 = idx - IX_DT0;
        int p = i6 / 20, k = i6 % 20;
        int l = 0, bcur = 0;
        for (;;) { int bs = (l + 1) * (2 * l + 1); if (p < bcur + bs) break; bcur += bs; ++l; }
        int r = p - bcur; int L = 2 * l + 1;
        int m = r / L; int n = r % L - l;
        double beta = M_PI * (2 * k + 1) / 40.0;
        wsf[WS_DT + i6] = (float)((double)L * dsmall(l, m, n, beta));
    }
}

// ---- fhat: block per (b,i) ----
extern "C" __global__ void __launch_bounds__(256) k_fhat(const float* __restrict__ x,
                                                          float* __restrict__ wsf) {
    __shared__ float  xs[3600];
    __shared__ float2 ems[610];
    __shared__ float2 Y[600];
    int tid = threadIdx.x;
    int bi = blockIdx.x;
    const float4* xp = (const float4*)(x + bi * 3600);
    for (int t = tid; t < 900; t += 256) ((float4*)xs)[t] = xp[t];
    const float2* gEm = (const float2*)(wsf + WS_EM);
    for (int t = tid; t < 600; t += 256) {
        int m = t / 60, j = t - m * 60;
        ems[m * 61 + j] = gEm[t];
    }
    __syncthreads();
    for (int it = tid; it < 600; it += 256) {
        int k = it / 10, m = it - k * 10;
        const float*  row = xs + k * 60;
        const float2* em  = ems + m * 61;
        float ar = 0.f, ai = 0.f;
        #pragma unroll 12
        for (int j = 0; j < 60; ++j) {
            float xv = row[j];
            float2 e = em[j];
            ar += xv * e.x; ai += xv * e.y;
        }
        Y[it] = make_float2(ar, ai);
    }
    __syncthreads();
    if (tid < 55) {
        int smi = tid;
        const int tri[11] = {0, 1, 3, 6, 10, 15, 21, 28, 36, 45, 55};
        int l = 0; while (smi >= tri[l + 1]) ++l;
        int m = smi - tri[l];
        const float* gW = wsf + WS_W;
        float ar = 0.f, ai = 0.f;
        for (int kk = 0; kk < 60; ++kk) {
            float wv = gW[kk * 55 + smi];
            float2 y = Y[kk * 10 + m];
            ar += wv * y.x; ai += wv * y.y;
        }
        int b = bi >> 1, i = bi & 1;
        ((float2*)(wsf + WS_FH))[b * 110 + smi * 2 + i] = make_float2(ar, ai);
    }
}

// ---- k_z: one thread per (po,p) -> gZ[po][p] float2 (no LDS, no sync) ----
extern "C" __global__ void __launch_bounds__(256) k_z(float* __restrict__ wsf) {
    int idx = blockIdx.x * 256 + threadIdx.x;
    if (idx >= 2560 * 715) return;
    int po = idx / 715, p = idx - po * 715;
    int b = po / 5, o = po - b * 5;
    int pk = ((const int*)(wsf + WS_PACK))[p];
    int smi = pk >> 7, sf = pk & 127;
    float4 f = ((const float4*)(wsf + WS_FH))[b * 55 + smi];
    float4 y = ((const float4*)(wsf + WS_Y))[o * 100 + sf];
    float zr = f.x * y.x + f.y * y.y + f.z * y.z + f.w * y.w;
    float zi = f.y * y.x - f.x * y.y + f.w * y.z - f.z * y.w;
    ((float2*)(wsf + WS_Z))[idx] = make_float2(zr, zi);
}

// unrolled F-sum for compile-time lmin L: steps l = L..9, straight-line,
// all loads independent -> full MLP. z read from GLOBAL (same values/order).
template<int L>
__device__ __forceinline__ void fsum(int m, int n, int ko, const float* __restrict__ gDT,
                                     const float2* __restrict__ zp, float& fr, float& fi) {
    const int baseL[10] = {0, 1, 7, 22, 50, 95, 161, 252, 372, 525};
    float dv[10 - L];
    float2 zv[10 - L];
    #pragma unroll
    for (int l = L; l < 10; ++l) {
        int p = baseL[l] + m * (2 * l + 1) + n + l;
        dv[l - L] = gDT[p * 20 + ko];
        zv[l - L] = zp[p];
    }
    #pragma unroll
    for (int l = L; l < 10; ++l) {
        fr += dv[l - L] * zv[l - L].x;
        fi += dv[l - L] * zv[l - L].y;
    }
}

// ---- k_F: chain-sum F from global z, write gF in B-frag layout ----
// grid 3200: blockIdx = nb*4 + q; q selects r = 4k+q (wave-uniform scalar).
// No LDS, no barriers -> occupancy VGPR-bound (~6 waves/SIMD).
extern "C" __global__ void __launch_bounds__(256) k_F(float* __restrict__ wsf) {
    int tid = threadIdx.x;
    int q  = blockIdx.x & 3;
    int nb = blockIdx.x >> 2;
    int n0 = nb * 64;
    int col = tid & 63;
    int n   = n0 + col;
    int po  = n / 20, ko = n - po * 20;
    int gg  = (n0 >> 4) + (col >> 4);
    int c15 = col & 15;
    const float*  gDT = wsf + WS_DT;
    const float2* zp  = ((const float2*)(wsf + WS_Z)) + po * 715;
    uint32_t*     gF  = (uint32_t*)(wsf + WS_F);
    int nit = (q < 2) ? 3072 : 3008;   // q<2: 48 r-values, else 47 (covers r<190)
    for (int it = tid; it < nit; it += 256) {
        int r = __builtin_amdgcn_readfirstlane(((it >> 6) << 2) | q);  // wave-uniform
        int m = r / 19;
        int nn = r - m * 19 - 9;
        int a = nn < 0 ? -nn : nn;
        int lmin = m > a ? m : a;
        float fr = 0.f, fi = 0.f;
        switch (lmin) {
            case 0: fsum<0>(m, nn, ko, gDT, zp, fr, fi); break;
            case 1: fsum<1>(m, nn, ko, gDT, zp, fr, fi); break;
            case 2: fsum<2>(m, nn, ko, gDT, zp, fr, fi); break;
            case 3: fsum<3>(m, nn, ko, gDT, zp, fr, fi); break;
            case 4: fsum<4>(m, nn, ko, gDT, zp, fr, fi); break;
            case 5: fsum<5>(m, nn, ko, gDT, zp, fr, fi); break;
            case 6: fsum<6>(m, nn, ko, gDT, zp, fr, fi); break;
            case 7: fsum<7>(m, nn, ko, gDT, zp, fr, fi); break;
            case 8: fsum<8>(m, nn, ko, gDT, zp, fr, fi); break;
            default: fsum<9>(m, nn, ko, gDT, zp, fr, fi); break;
        }
        int chunk = r >> 4, w5 = (2 * r) & 31;
        int qp = w5 >> 3, dwi = (w5 & 7) >> 1;
        union { _Float16 h[2]; uint32_t u; } fv;
        fv.h[0] = (_Float16)fr; fv.h[1] = (_Float16)fi;
        gF[((chunk * 3200 + gg) * 64 + (qp * 16 + c15)) * 4 + dwi] = fv.u;
    }
    if (q == 0 && tid < 128) {   // zero K-padding (kidx 380..383)
        int cc = tid >> 1, dwi = 2 + (tid & 1);
        int g2 = (n0 >> 4) + (cc >> 4);
        gF[((11 * 3200 + g2) * 64 + (48 + (cc & 15))) * 4 + dwi] = 0u;
    }
}

// ---- k_gemm2: LDS-free streaming MFMA GEMM, software-pipelined (v7 form) ----
extern "C" __global__ void __launch_bounds__(256) k_gemm2(const float* __restrict__ wsf,
                                                           const float* __restrict__ bias,
                                                           float* __restrict__ out) {
    int tid = threadIdx.x;
    int n0 = blockIdx.x * 64;
    int wave = tid >> 6, lane = tid & 63;
    int g0 = n0 >> 4;
    const half8* gA = (const half8*)(wsf + WS_AP);
    const half8* gB = (const half8*)(wsf + WS_F);
    int t0 = wave * 7;
    int ntile = (wave < 3) ? 7 : 4;          // tiles 21..24 real; 25..27 pad

    f32x4 acc[7][4];
    #pragma unroll
    for (int tt = 0; tt < 7; ++tt)
        #pragma unroll
        for (int f = 0; f < 4; ++f) acc[tt][f] = (f32x4){0.f, 0.f, 0.f, 0.f};

    half8 bufB[2][4], bufA[2][7];
    #pragma unroll
    for (int f = 0; f < 4; ++f) bufB[0][f] = gB[(g0 + f) * 64 + lane];
    #pragma unroll
    for (int tt = 0; tt < 7; ++tt)
        if (tt < ntile) bufA[0][tt] = gA[(t0 + tt) * 64 + lane];

    #pragma unroll
    for (int c = 0; c < 12; ++c) {
        const int cur = c & 1, nxt = cur ^ 1;
        if (c < 11) {
            #pragma unroll
            for (int f = 0; f < 4; ++f)
                bufB[nxt][f] = gB[((c + 1) * 3200 + g0 + f) * 64 + lane];
            #pragma unroll
            for (int tt = 0; tt < 7; ++tt)
                if (tt < ntile) bufA[nxt][tt] = gA[((c + 1) * 28 + t0 + tt) * 64 + lane];
        }
        #pragma unroll
        for (int tt = 0; tt < 7; ++tt) {
            if (tt < ntile) {
                #pragma unroll
                for (int f = 0; f < 4; ++f)
                    acc[tt][f] = __builtin_amdgcn_mfma_f32_16x16x32_f16(bufA[cur][tt], bufB[cur][f], acc[tt][f], 0, 0, 0);
            }
        }
    }

    int quad4 = (lane >> 4) << 2, col15 = lane & 15;
    float bo_f[4];
    #pragma unroll
    for (int f = 0; f < 4; ++f) bo_f[f] = bias[((n0 + f * 16 + col15) / 20) % 5];
    #pragma unroll
    for (int tt = 0; tt < 7; ++tt) {
        if (tt < ntile) {
            int pqb = (t0 + tt) * 16 + quad4;
            #pragma unroll
            for (int f = 0; f < 4; ++f) {
                int n = n0 + f * 16 + col15;
                float bo = bo_f[f];
                float4 v = make_float4(acc[tt][f].x + bo, acc[tt][f].y + bo,
                                       acc[tt][f].z + bo, acc[tt][f].w + bo);
                *(float4*)(out + n * 400 + pqb) = v;
            }
        }
    }
}

extern "C" void kernel_launch(void* const* d_in, const int* in_sizes, int n_in,
                              void* d_out, int out_size, void* d_ws, size_t ws_size,
                              hipStream_t stream) {
    const float* x    = (const float*)d_in[0];
    const float* kern = (const float*)d_in[1];
    const float* bias = (const float*)d_in[2];
    float* out = (float*)d_out;
    float* wsf = (float*)d_ws;
    k_setup_w    <<<1,    64,  0, stream>>>(wsf);
    k_setup_const<<<3003, 64,  0, stream>>>(wsf, kern);
    k_fhat       <<<1024, 256, 0, stream>>>(x, wsf);
    k_z          <<<7150, 256, 0, stream>>>(wsf);
    k_F          <<<3200, 256, 0, stream>>>(wsf);
    k_gemm2      <<<800,  256, 0, stream>>>(wsf, bias, out);
}

// Round 8
// 182.153 us; speedup vs baseline: 1.1223x; 1.1223x over previous
//
#include <hip/hip_runtime.h>
#include <math.h>
#include <stdint.h>

// ---------------------------------------------------------------------------
// v11: v7 structure (best measured) + two fixes:
//  - k_zF: zsh packed fp16 (v5-verified numerics) -> LDS 32.6->21.2 KB ->
//    7 blocks/CU cap, all 6.25 offered blocks resident (~78% occ).
//  - k_gemm2: whole 48KB B-slice staged to LDS in ONE burst (12 indep loads
//    per wave, latency paid once) + v9 tile-split (acc[4][4], grid 1600)
//    -> 12 waves/CU, no per-c global B stalls. Bit-identical math.
// Pipeline: setup_w -> setup_const -> fhat -> zF -> gemm2.
// ---------------------------------------------------------------------------

typedef _Float16 half8 __attribute__((ext_vector_type(8)));
typedef float    f32x4 __attribute__((ext_vector_type(4)));

// workspace float offsets
#define WS_W    128     // gW [k60][sm55]                 3300
#define WS_Y    17760   // gyhat [o5][s100][i2] float2
#define WS_EM   19776   // gEm [m10][j60] float2
#define WS_TRIG 20992   // 20 dbl sin + 20 dbl cos (ex-gRT region)
#define WS_PACK 21184   // gPack[715] int
#define WS_AP   21952   // A-pack 172032 fp16
#define WS_FH   107968  // gfhat [b512][sm55][i2] float2 = 112640 floats
#define WS_DT   220608  // gDT [p715][k20] = 14300 floats
#define WS_F    234908  // gF 9,830,400 dwords (39.3 MB) B-frag layout

// setup idx ranges (non-overlapping)
#define IX_Y0    3300
#define IX_EM0   4300
#define IX_RT0   4900
#define IX_PACK0 5090
#define IX_AP0   5805
#define IX_DT0   177837   // IX_AP0 + 172032
#define N_SETUP  192137   // + 14300

__device__ __forceinline__ double ipow_d(double x, int e) {
    double r = 1.0;
    for (int i = 0; i < e; ++i) r *= x;
    return r;
}

__device__ double dsmall(int l, int mp, int m, double beta) {
    double fact[20];
    fact[0] = 1.0;
    for (int i = 1; i < 20; ++i) fact[i] = fact[i - 1] * (double)i;
    double cb = cos(0.5 * beta), sb = sin(0.5 * beta);
    double pref = sqrt(fact[l + m] * fact[l - m] * fact[l + mp] * fact[l - mp]);
    int s0 = m - mp; if (s0 < 0) s0 = 0;
    int s1 = l + m;  if (l - mp < s1) s1 = l - mp;
    double tot = 0.0;
    for (int s = s0; s <= s1; ++s) {
        double den = fact[l + m - s] * fact[s] * fact[mp - m + s] * fact[l - mp - s];
        double sgn = ((mp - m + s) & 1) ? -1.0 : 1.0;
        tot += sgn / den * ipow_d(cb, 2 * l + m - mp - 2 * s) * ipow_d(sb, mp - m + 2 * s);
    }
    return pref * tot;
}

extern "C" __global__ void k_setup_w(float* wsf) {
    double* w = (double*)wsf;
    int t = threadIdx.x;
    if (t < 60) {
        double beta = M_PI * (2 * t + 1) / 120.0;
        double sum = 0.0;
        for (int k = 0; k < 30; ++k)
            sum += sin((double)((2 * t + 1) * (2 * k + 1)) * M_PI / 120.0) / (double)(2 * k + 1);
        w[t] = (2.0 / 30.0) * sin(beta) * sum;
    }
    if (t < 20) {   // A-pack trig table: sin/cos(pi*t/10), exact same expr as original
        double ang = M_PI * (double)t / 10.0;
        ((double*)(wsf + WS_TRIG))[t]      = sin(ang);
        ((double*)(wsf + WS_TRIG))[20 + t] = cos(ang);
    }
}

extern "C" __global__ void k_setup_const(float* wsf, const float* __restrict__ kern) {
    const double* w = (const double*)wsf;
    const int tri[11] = {0, 1, 3, 6, 10, 15, 21, 28, 36, 45, 55};
    int idx = blockIdx.x * 64 + threadIdx.x;
    if (idx < IX_Y0) {                      // gW [k][sm]
        int k = idx / 55, smi = idx % 55;
        int l = 0; while (smi >= tri[l + 1]) ++l;
        int m = smi - tri[l];
        double beta = M_PI * (2 * k + 1) / 120.0;
        wsf[WS_W + idx] = (float)(w[k] * dsmall(l, m, 0, beta));
    } else if (idx < IX_EM0) {              // gyhat [o][s][i]
        int i3 = idx - IX_Y0;
        int o = i3 / 200, r5 = i3 % 200;
        int s = r5 / 2, i = r5 % 2;
        int l = 0; while ((l + 1) * (l + 1) <= s) ++l;
        int n = s - l * l - l;
        double dv = dsmall(l, n, 0, M_PI / 160.0);
        const double SC = 1.0 / sqrt(6.0 * 2.0 * 10000.0 / 900.0);
        double ar = 0.0, ai = 0.0;
        for (int g = 0; g < 6; ++g) {
            double kv = (double)kern[i * 30 + o * 6 + g];
            double ang = (double)n * M_PI * (double)g / 3.0;
            ar += kv * cos(ang);
            ai -= kv * sin(ang);
        }
        ((float2*)(wsf + WS_Y))[i3] = make_float2((float)(SC * dv * ar), (float)(SC * dv * ai));
    } else if (idx < IX_RT0) {              // gEm [m][j]
        int t = idx - IX_EM0; int m = t / 60, j = t % 60;
        double a = 2.0 * M_PI * (double)(m * j) / 60.0;
        ((float2*)(wsf + WS_EM))[t] = make_float2((float)cos(a), (float)(-sin(a)));
    } else if (idx < IX_PACK0) {
        // ex-gRT region holds the trig table (written by k_setup_w)
    } else if (idx < IX_AP0) {              // gPack[715]
        int p = idx - IX_PACK0;
        int l = 0, bcur = 0;
        for (;;) { int bs = (l + 1) * (2 * l + 1); if (p < bcur + bs) break; bcur += bs; ++l; }
        int r = p - bcur; int L = 2 * l + 1;
        int m = r / L; int n = r % L - l;
        int smi = tri[l] + m; int sf = l * l + l + n;
        ((int*)(wsf + WS_PACK))[p] = smi * 128 + sf;
    } else if (idx < IX_DT0) {              // A-pack (A-fragment lane order), table lookup
        int ap = idx - IX_AP0;
        int j = ap & 7, lane = (ap >> 3) & 63, tc = ap >> 9;
        int t = tc % 28, c = tc / 28;
        int pq = t * 16 + (lane & 15);
        int kidx = c * 32 + ((lane >> 4) << 3) + j;
        double val = 0.0;
        if (pq < 400 && kidx < 380) {
            int r = kidx >> 1, cpart = kidx & 1;
            int m = r / 19, nn = r % 19, n = nn - 9;
            int p = pq / 20, q = pq % 20;
            int th = ((m * p + n * q) % 20 + 20) % 20;
            double wm = m ? 2.0 : 1.0;
            const double* st = (const double*)(wsf + WS_TRIG);
            val = cpart ? (-wm * st[th]) : (wm * st[20 + th]);
        }
        ((_Float16*)(wsf + WS_AP))[ap] = (_Float16)val;
    } else if (idx < N_SETUP) {             // gDT [p][k] transposed
        int i6 = idx - IX_DT0;
        int p = i6 / 20, k = i6 % 20;
        int l = 0, bcur = 0;
        for (;;) { int bs = (l + 1) * (2 * l + 1); if (p < bcur + bs) break; bcur += bs; ++l; }
        int r = p - bcur; int L = 2 * l + 1;
        int m = r / L; int n = r % L - l;
        double beta = M_PI * (2 * k + 1) / 40.0;
        wsf[WS_DT + i6] = (float)((double)L * dsmall(l, m, n, beta));
    }
}

// ---- fhat: block per (b,i) ----
extern "C" __global__ void __launch_bounds__(256) k_fhat(const float* __restrict__ x,
                                                          float* __restrict__ wsf) {
    __shared__ float  xs[3600];
    __shared__ float2 ems[610];
    __shared__ float2 Y[600];
    int tid = threadIdx.x;
    int bi = blockIdx.x;
    const float4* xp = (const float4*)(x + bi * 3600);
    for (int t = tid; t < 900; t += 256) ((float4*)xs)[t] = xp[t];
    const float2* gEm = (const float2*)(wsf + WS_EM);
    for (int t = tid; t < 600; t += 256) {
        int m = t / 60, j = t - m * 60;
        ems[m * 61 + j] = gEm[t];
    }
    __syncthreads();
    for (int it = tid; it < 600; it += 256) {
        int k = it / 10, m = it - k * 10;
        const float*  row = xs + k * 60;
        const float2* em  = ems + m * 61;
        float ar = 0.f, ai = 0.f;
        #pragma unroll 12
        for (int j = 0; j < 60; ++j) {
            float xv = row[j];
            float2 e = em[j];
            ar += xv * e.x; ai += xv * e.y;
        }
        Y[it] = make_float2(ar, ai);
    }
    __syncthreads();
    if (tid < 55) {
        int smi = tid;
        const int tri[11] = {0, 1, 3, 6, 10, 15, 21, 28, 36, 45, 55};
        int l = 0; while (smi >= tri[l + 1]) ++l;
        int m = smi - tri[l];
        const float* gW = wsf + WS_W;
        float ar = 0.f, ai = 0.f;
        for (int kk = 0; kk < 60; ++kk) {
            float wv = gW[kk * 55 + smi];
            float2 y = Y[kk * 10 + m];
            ar += wv * y.x; ai += wv * y.y;
        }
        int b = bi >> 1, i = bi & 1;
        ((float2*)(wsf + WS_FH))[b * 110 + smi * 2 + i] = make_float2(ar, ai);
    }
}

// unrolled F-sum for compile-time lmin L: steps l = L..9, straight-line,
// all loads independent -> full MLP. z is fp16-packed in LDS.
template<int L>
__device__ __forceinline__ void fsum(int m, int n, int ko, const float* __restrict__ gDT,
                                     const uint32_t* zp, float& fr, float& fi) {
    const int baseL[10] = {0, 1, 7, 22, 50, 95, 161, 252, 372, 525};
    float dv[10 - L];
    uint32_t zv[10 - L];
    #pragma unroll
    for (int l = L; l < 10; ++l) {
        int p = baseL[l] + m * (2 * l + 1) + n + l;
        dv[l - L] = gDT[p * 20 + ko];
        zv[l - L] = zp[p];
    }
    #pragma unroll
    for (int l = L; l < 10; ++l) {
        union { uint32_t u; _Float16 h[2]; } zc; zc.u = zv[l - L];
        fr += dv[l - L] * (float)zc.h[0];
        fi += dv[l - L] * (float)zc.h[1];
    }
}

// ---- k_zF: z + F, write gF in B-frag layout ----
// v11: zsh fp16-packed -> LDS 21.2 KB -> 7 blocks/CU cap (grid 1600 fully
// resident). Otherwise v7 logic (lmin switch, 2-way r-split).
extern "C" __global__ void __launch_bounds__(256) k_zF(float* __restrict__ wsf) {
    __shared__ uint32_t zsh[2860];    // z [pp4][p715] fp16-packed (11.4 KB)
    __shared__ float4 fbl4[110];
    __shared__ float4 yol4[500];
    int tid = threadIdx.x;
    int half = blockIdx.x & 1;
    int nb   = blockIdx.x >> 1;
    int n0 = nb * 64;
    int PO0 = n0 / 20;
    int bf = PO0 / 5;

    const float4* gfh4 = (const float4*)(wsf + WS_FH);
    for (int t = tid; t < 110; t += 256) {
        int bsel = t / 55, i55 = t - bsel * 55;
        int b = bf + bsel;
        fbl4[t] = (b < 512) ? gfh4[b * 55 + i55] : make_float4(0.f, 0.f, 0.f, 0.f);
    }
    for (int t = tid; t < 500; t += 256) yol4[t] = ((const float4*)(wsf + WS_Y))[t];
    __syncthreads();
    const int* gPack = (const int*)(wsf + WS_PACK);
    for (int pp = 0; pp < 4; ++pp) {
        int po = PO0 + pp;
        int b_loc = po / 5 - bf, o = po % 5;
        for (int p = tid; p < 715; p += 256) {
            int pk = gPack[p];
            int smi = pk >> 7, sf = pk & 127;
            float4 f = fbl4[b_loc * 55 + smi];
            float4 y = yol4[o * 100 + sf];
            float zr = f.x * y.x + f.y * y.y + f.z * y.z + f.w * y.w;
            float zi = f.y * y.x - f.x * y.y + f.w * y.z - f.z * y.w;
            union { _Float16 h[2]; uint32_t u; } cv;
            cv.h[0] = (_Float16)zr; cv.h[1] = (_Float16)zi;
            zsh[pp * 715 + p] = cv.u;
        }
    }
    __syncthreads();

    int col = tid & 63;
    int ko  = (n0 + col) % 20;
    int pp  = ((n0 % 20) + col) / 20;
    int gg  = (n0 >> 4) + (col >> 4);
    int c15 = col & 15;
    const float* gDT = wsf + WS_DT;
    uint32_t*    gF  = (uint32_t*)(wsf + WS_F);
    const uint32_t* zp = zsh + pp * 715;
    for (int it = tid; it < 6080; it += 256) {
        int r = __builtin_amdgcn_readfirstlane(((it >> 6) << 1) | half);  // wave-uniform scalar
        int m = r / 19;
        int n = r - m * 19 - 9;
        int a = n < 0 ? -n : n;
        int lmin = m > a ? m : a;
        float fr = 0.f, fi = 0.f;
        switch (lmin) {
            case 0: fsum<0>(m, n, ko, gDT, zp, fr, fi); break;
            case 1: fsum<1>(m, n, ko, gDT, zp, fr, fi); break;
            case 2: fsum<2>(m, n, ko, gDT, zp, fr, fi); break;
            case 3: fsum<3>(m, n, ko, gDT, zp, fr, fi); break;
            case 4: fsum<4>(m, n, ko, gDT, zp, fr, fi); break;
            case 5: fsum<5>(m, n, ko, gDT, zp, fr, fi); break;
            case 6: fsum<6>(m, n, ko, gDT, zp, fr, fi); break;
            case 7: fsum<7>(m, n, ko, gDT, zp, fr, fi); break;
            case 8: fsum<8>(m, n, ko, gDT, zp, fr, fi); break;
            default: fsum<9>(m, n, ko, gDT, zp, fr, fi); break;
        }
        int chunk = r >> 4, w5 = (2 * r) & 31;
        int qp = w5 >> 3, dwi = (w5 & 7) >> 1;
        union { _Float16 h[2]; uint32_t u; } fv;
        fv.h[0] = (_Float16)fr; fv.h[1] = (_Float16)fi;
        gF[((chunk * 3200 + gg) * 64 + (qp * 16 + c15)) * 4 + dwi] = fv.u;
    }
    if (half == 0 && tid < 128) {   // zero K-padding (kidx 380..383)
        int cc = tid >> 1, dwi = 2 + (tid & 1);
        int g2 = (n0 >> 4) + (cc >> 4);
        gF[((11 * 3200 + g2) * 64 + (48 + (cc & 15))) * 4 + dwi] = 0u;
    }
}

// ---- k_gemm2: B staged wholly in LDS (one burst), tile-split 2x ----
// grid 1600: block pair (h=0,1) shares n0; h=0 -> tiles 0..12, h=1 -> 13..24.
// acc[4][4] (64 VGPR); whole 48KB B-slice ds-staged once, then MFMA from LDS.
extern "C" __global__ void __launch_bounds__(256) k_gemm2(const float* __restrict__ wsf,
                                                           const float* __restrict__ bias,
                                                           float* __restrict__ out) {
    __shared__ __align__(16) _Float16 Bsh[12 * 4 * 64 * 8];   // 48 KB
    int tid = threadIdx.x;
    int h  = blockIdx.x & 1;
    int n0 = (blockIdx.x >> 1) * 64;
    int wave = tid >> 6, lane = tid & 63;
    int g0 = n0 >> 4;
    const half8* gA = (const half8*)(wsf + WS_AP);
    const half8* gB = (const half8*)(wsf + WS_F);
    half8* lB = (half8*)Bsh;

    // ---- stage ALL B for this n0 into LDS: 12 frags/wave, loads batched ----
    half8 stg[12];
    #pragma unroll
    for (int i = 0; i < 12; ++i) {
        int cf = wave * 12 + i;                  // cf = c*4 + f, 0..47
        int c = cf >> 2, f = cf & 3;
        stg[i] = gB[(c * 3200 + g0 + f) * 64 + lane];
    }
    #pragma unroll
    for (int i = 0; i < 12; ++i)
        lB[(wave * 12 + i) * 64 + lane] = stg[i];

    int nt = (h == 0 && wave == 0) ? 4 : 3;
    int t0 = h * 13 + (h == 0 ? (wave == 0 ? 0 : 4 + 3 * (wave - 1)) : 3 * wave);

    f32x4 acc[4][4];
    #pragma unroll
    for (int tt = 0; tt < 4; ++tt)
        #pragma unroll
        for (int f = 0; f < 4; ++f) acc[tt][f] = (f32x4){0.f, 0.f, 0.f, 0.f};

    half8 bufA[2][4];
    #pragma unroll
    for (int tt = 0; tt < 4; ++tt)
        if (tt < nt) bufA[0][tt] = gA[(t0 + tt) * 64 + lane];

    __syncthreads();   // B resident in LDS

    #pragma unroll
    for (int c = 0; c < 12; ++c) {
        const int cur = c & 1, nxt = cur ^ 1;
        if (c < 11) {
            #pragma unroll
            for (int tt = 0; tt < 4; ++tt)
                if (tt < nt) bufA[nxt][tt] = gA[((c + 1) * 28 + t0 + tt) * 64 + lane];
        }
        half8 bB[4];
        #pragma unroll
        for (int f = 0; f < 4; ++f) bB[f] = lB[(c * 4 + f) * 64 + lane];
        #pragma unroll
        for (int tt = 0; tt < 4; ++tt) {
            if (tt < nt) {
                #pragma unroll
                for (int f = 0; f < 4; ++f)
                    acc[tt][f] = __builtin_amdgcn_mfma_f32_16x16x32_f16(bufA[cur][tt], bB[f], acc[tt][f], 0, 0, 0);
            }
        }
    }

    int quad4 = (lane >> 4) << 2, col15 = lane & 15;
    float bo_f[4];
    #pragma unroll
    for (int f = 0; f < 4; ++f) bo_f[f] = bias[((n0 + f * 16 + col15) / 20) % 5];
    #pragma unroll
    for (int tt = 0; tt < 4; ++tt) {
        if (tt < nt) {
            int pqb = (t0 + tt) * 16 + quad4;
            #pragma unroll
            for (int f = 0; f < 4; ++f) {
                int n = n0 + f * 16 + col15;
                float bo = bo_f[f];
                float4 v = make_float4(acc[tt][f].x + bo, acc[tt][f].y + bo,
                                       acc[tt][f].z + bo, acc[tt][f].w + bo);
                *(float4*)(out + n * 400 + pqb) = v;
            }
        }
    }
}

extern "C" void kernel_launch(void* const* d_in, const int* in_sizes, int n_in,
                              void* d_out, int out_size, void* d_ws, size_t ws_size,
                              hipStream_t stream) {
    const float* x    = (const float*)d_in[0];
    const float* kern = (const float*)d_in[1];
    const float* bias = (const float*)d_in[2];
    float* out = (float*)d_out;
    float* wsf = (float*)d_ws;
    k_setup_w    <<<1,    64,  0, stream>>>(wsf);
    k_setup_const<<<3003, 64,  0, stream>>>(wsf, kern);
    k_fhat       <<<1024, 256, 0, stream>>>(x, wsf);
    k_zF         <<<1600, 256, 0, stream>>>(wsf);
    k_gemm2      <<<1600, 256, 0, stream>>>(wsf, bias, out);
}

// Round 9
// 179.034 us; speedup vs baseline: 1.1418x; 1.0174x over previous
//
#include <hip/hip_runtime.h>
#include <math.h>
#include <stdint.h>

// ---------------------------------------------------------------------------
// v12: v11 + k_zF F-phase r-QUAD restructure:
//  - one thread computes r = 4j..4j+3 chains -> ONE dense uint4 store
//    (was 4x scattered 4B dwords at stride 16B -> ~4x sector amplification).
//  - quad 47's r=190,191 write the K-padding zeros for free (padding pass
//    deleted). Bit-identical math (same fsum bodies / values / pack).
// k_gemm2 (B-in-LDS burst + tile-split) and fp16 zsh kept from v11.
// Measured decomposition: ~104us harness poison fills + ~6.4us small kernels
// are fixed; zF (~40) + gemm2 (~32) are the addressable budget.
// Pipeline: setup_w -> setup_const -> fhat -> zF -> gemm2.
// ---------------------------------------------------------------------------

typedef _Float16 half8 __attribute__((ext_vector_type(8)));
typedef float    f32x4 __attribute__((ext_vector_type(4)));

// workspace float offsets
#define WS_W    128     // gW [k60][sm55]                 3300
#define WS_Y    17760   // gyhat [o5][s100][i2] float2
#define WS_EM   19776   // gEm [m10][j60] float2
#define WS_TRIG 20992   // 20 dbl sin + 20 dbl cos (ex-gRT region)
#define WS_PACK 21184   // gPack[715] int
#define WS_AP   21952   // A-pack 172032 fp16
#define WS_FH   107968  // gfhat [b512][sm55][i2] float2 = 112640 floats
#define WS_DT   220608  // gDT [p715][k20] = 14300 floats
#define WS_F    234908  // gF 9,830,400 dwords (39.3 MB) B-frag layout

// setup idx ranges (non-overlapping)
#define IX_Y0    3300
#define IX_EM0   4300
#define IX_RT0   4900
#define IX_PACK0 5090
#define IX_AP0   5805
#define IX_DT0   177837   // IX_AP0 + 172032
#define N_SETUP  192137   // + 14300

__device__ __forceinline__ double ipow_d(double x, int e) {
    double r = 1.0;
    for (int i = 0; i < e; ++i) r *= x;
    return r;
}

__device__ double dsmall(int l, int mp, int m, double beta) {
    double fact[20];
    fact[0] = 1.0;
    for (int i = 1; i < 20; ++i) fact[i] = fact[i - 1] * (double)i;
    double cb = cos(0.5 * beta), sb = sin(0.5 * beta);
    double pref = sqrt(fact[l + m] * fact[l - m] * fact[l + mp] * fact[l - mp]);
    int s0 = m - mp; if (s0 < 0) s0 = 0;
    int s1 = l + m;  if (l - mp < s1) s1 = l - mp;
    double tot = 0.0;
    for (int s = s0; s <= s1; ++s) {
        double den = fact[l + m - s] * fact[s] * fact[mp - m + s] * fact[l - mp - s];
        double sgn = ((mp - m + s) & 1) ? -1.0 : 1.0;
        tot += sgn / den * ipow_d(cb, 2 * l + m - mp - 2 * s) * ipow_d(sb, mp - m + 2 * s);
    }
    return pref * tot;
}

extern "C" __global__ void k_setup_w(float* wsf) {
    double* w = (double*)wsf;
    int t = threadIdx.x;
    if (t < 60) {
        double beta = M_PI * (2 * t + 1) / 120.0;
        double sum = 0.0;
        for (int k = 0; k < 30; ++k)
            sum += sin((double)((2 * t + 1) * (2 * k + 1)) * M_PI / 120.0) / (double)(2 * k + 1);
        w[t] = (2.0 / 30.0) * sin(beta) * sum;
    }
    if (t < 20) {   // A-pack trig table: sin/cos(pi*t/10), exact same expr as original
        double ang = M_PI * (double)t / 10.0;
        ((double*)(wsf + WS_TRIG))[t]      = sin(ang);
        ((double*)(wsf + WS_TRIG))[20 + t] = cos(ang);
    }
}

extern "C" __global__ void k_setup_const(float* wsf, const float* __restrict__ kern) {
    const double* w = (const double*)wsf;
    const int tri[11] = {0, 1, 3, 6, 10, 15, 21, 28, 36, 45, 55};
    int idx = blockIdx.x * 64 + threadIdx.x;
    if (idx < IX_Y0) {                      // gW [k][sm]
        int k = idx / 55, smi = idx % 55;
        int l = 0; while (smi >= tri[l + 1]) ++l;
        int m = smi - tri[l];
        double beta = M_PI * (2 * k + 1) / 120.0;
        wsf[WS_W + idx] = (float)(w[k] * dsmall(l, m, 0, beta));
    } else if (idx < IX_EM0) {              // gyhat [o][s][i]
        int i3 = idx - IX_Y0;
        int o = i3 / 200, r5 = i3 % 200;
        int s = r5 / 2, i = r5 % 2;
        int l = 0; while ((l + 1) * (l + 1) <= s) ++l;
        int n = s - l * l - l;
        double dv = dsmall(l, n, 0, M_PI / 160.0);
        const double SC = 1.0 / sqrt(6.0 * 2.0 * 10000.0 / 900.0);
        double ar = 0.0, ai = 0.0;
        for (int g = 0; g < 6; ++g) {
            double kv = (double)kern[i * 30 + o * 6 + g];
            double ang = (double)n * M_PI * (double)g / 3.0;
            ar += kv * cos(ang);
            ai -= kv * sin(ang);
        }
        ((float2*)(wsf + WS_Y))[i3] = make_float2((float)(SC * dv * ar), (float)(SC * dv * ai));
    } else if (idx < IX_RT0) {              // gEm [m][j]
        int t = idx - IX_EM0; int m = t / 60, j = t % 60;
        double a = 2.0 * M_PI * (double)(m * j) / 60.0;
        ((float2*)(wsf + WS_EM))[t] = make_float2((float)cos(a), (float)(-sin(a)));
    } else if (idx < IX_PACK0) {
        // ex-gRT region holds the trig table (written by k_setup_w)
    } else if (idx < IX_AP0) {              // gPack[715]
        int p = idx - IX_PACK0;
        int l = 0, bcur = 0;
        for (;;) { int bs = (l + 1) * (2 * l + 1); if (p < bcur + bs) break; bcur += bs; ++l; }
        int r = p - bcur; int L = 2 * l + 1;
        int m = r / L; int n = r % L - l;
        int smi = tri[l] + m; int sf = l * l + l + n;
        ((int*)(wsf + WS_PACK))[p] = smi * 128 + sf;
    } else if (idx < IX_DT0) {              // A-pack (A-fragment lane order), table lookup
        int ap = idx - IX_AP0;
        int j = ap & 7, lane = (ap >> 3) & 63, tc = ap >> 9;
        int t = tc % 28, c = tc / 28;
        int pq = t * 16 + (lane & 15);
        int kidx = c * 32 + ((lane >> 4) << 3) + j;
        double val = 0.0;
        if (pq < 400 && kidx < 380) {
            int r = kidx >> 1, cpart = kidx & 1;
            int m = r / 19, nn = r % 19, n = nn - 9;
            int p = pq / 20, q = pq % 20;
            int th = ((m * p + n * q) % 20 + 20) % 20;
            double wm = m ? 2.0 : 1.0;
            const double* st = (const double*)(wsf + WS_TRIG);
            val = cpart ? (-wm * st[th]) : (wm * st[20 + th]);
        }
        ((_Float16*)(wsf + WS_AP))[ap] = (_Float16)val;
    } else if (idx < N_SETUP) {             // gDT [p][k] transposed
        int i6 = idx - IX_DT0;
        int p = i6 / 20, k = i6 % 20;
        int l = 0, bcur = 0;
        for (;;) { int bs = (l + 1) * (2 * l + 1); if (p < bcur + bs) break; bcur += bs; ++l; }
        int r = p - bcur; int L = 2 * l + 1;
        int m = r / L; int n = r % L - l;
        double beta = M_PI * (2 * k + 1) / 40.0;
        wsf[WS_DT + i6] = (float)((double)L * dsmall(l, m, n, beta));
    }
}

// ---- fhat: block per (b,i) ----
extern "C" __global__ void __launch_bounds__(256) k_fhat(const float* __restrict__ x,
                                                          float* __restrict__ wsf) {
    __shared__ float  xs[3600];
    __shared__ float2 ems[610];
    __shared__ float2 Y[600];
    int tid = threadIdx.x;
    int bi = blockIdx.x;
    const float4* xp = (const float4*)(x + bi * 3600);
    for (int t = tid; t < 900; t += 256) ((float4*)xs)[t] = xp[t];
    const float2* gEm = (const float2*)(wsf + WS_EM);
    for (int t = tid; t < 600; t += 256) {
        int m = t / 60, j = t - m * 60;
        ems[m * 61 + j] = gEm[t];
    }
    __syncthreads();
    for (int it = tid; it < 600; it += 256) {
        int k = it / 10, m = it - k * 10;
        const float*  row = xs + k * 60;
        const float2* em  = ems + m * 61;
        float ar = 0.f, ai = 0.f;
        #pragma unroll 12
        for (int j = 0; j < 60; ++j) {
            float xv = row[j];
            float2 e = em[j];
            ar += xv * e.x; ai += xv * e.y;
        }
        Y[it] = make_float2(ar, ai);
    }
    __syncthreads();
    if (tid < 55) {
        int smi = tid;
        const int tri[11] = {0, 1, 3, 6, 10, 15, 21, 28, 36, 45, 55};
        int l = 0; while (smi >= tri[l + 1]) ++l;
        int m = smi - tri[l];
        const float* gW = wsf + WS_W;
        float ar = 0.f, ai = 0.f;
        for (int kk = 0; kk < 60; ++kk) {
            float wv = gW[kk * 55 + smi];
            float2 y = Y[kk * 10 + m];
            ar += wv * y.x; ai += wv * y.y;
        }
        int b = bi >> 1, i = bi & 1;
        ((float2*)(wsf + WS_FH))[b * 110 + smi * 2 + i] = make_float2(ar, ai);
    }
}

// unrolled F-sum for compile-time lmin L: steps l = L..9, straight-line,
// all loads independent -> full MLP. z is fp16-packed in LDS.
template<int L>
__device__ __forceinline__ void fsum(int m, int n, int ko, const float* __restrict__ gDT,
                                     const uint32_t* zp, float& fr, float& fi) {
    const int baseL[10] = {0, 1, 7, 22, 50, 95, 161, 252, 372, 525};
    float dv[10 - L];
    uint32_t zv[10 - L];
    #pragma unroll
    for (int l = L; l < 10; ++l) {
        int p = baseL[l] + m * (2 * l + 1) + n + l;
        dv[l - L] = gDT[p * 20 + ko];
        zv[l - L] = zp[p];
    }
    #pragma unroll
    for (int l = L; l < 10; ++l) {
        union { uint32_t u; _Float16 h[2]; } zc; zc.u = zv[l - L];
        fr += dv[l - L] * (float)zc.h[0];
        fi += dv[l - L] * (float)zc.h[1];
    }
}

// ---- k_zF: z + F, write gF in B-frag layout ----
// v12: F-phase processes r-QUADS (r = 4j..4j+3 share the gF slot; dwi = r&3)
// -> one dense uint4 store per (quad, col). Quad 47's r=190,191 produce the
// K-padding zeros. Grid 1600: block pair (even/odd quads) shares n0.
extern "C" __global__ void __launch_bounds__(256) k_zF(float* __restrict__ wsf) {
    __shared__ uint32_t zsh[2860];    // z [pp4][p715] fp16-packed (11.4 KB)
    __shared__ float4 fbl4[110];
    __shared__ float4 yol4[500];
    int tid = threadIdx.x;
    int half = blockIdx.x & 1;
    int nb   = blockIdx.x >> 1;
    int n0 = nb * 64;
    int PO0 = n0 / 20;
    int bf = PO0 / 5;

    const float4* gfh4 = (const float4*)(wsf + WS_FH);
    for (int t = tid; t < 110; t += 256) {
        int bsel = t / 55, i55 = t - bsel * 55;
        int b = bf + bsel;
        fbl4[t] = (b < 512) ? gfh4[b * 55 + i55] : make_float4(0.f, 0.f, 0.f, 0.f);
    }
    for (int t = tid; t < 500; t += 256) yol4[t] = ((const float4*)(wsf + WS_Y))[t];
    __syncthreads();
    const int* gPack = (const int*)(wsf + WS_PACK);
    for (int pp = 0; pp < 4; ++pp) {
        int po = PO0 + pp;
        int b_loc = po / 5 - bf, o = po % 5;
        for (int p = tid; p < 715; p += 256) {
            int pk = gPack[p];
            int smi = pk >> 7, sf = pk & 127;
            float4 f = fbl4[b_loc * 55 + smi];
            float4 y = yol4[o * 100 + sf];
            float zr = f.x * y.x + f.y * y.y + f.z * y.z + f.w * y.w;
            float zi = f.y * y.x - f.x * y.y + f.w * y.z - f.z * y.w;
            union { _Float16 h[2]; uint32_t u; } cv;
            cv.h[0] = (_Float16)zr; cv.h[1] = (_Float16)zi;
            zsh[pp * 715 + p] = cv.u;
        }
    }
    __syncthreads();

    int col = tid & 63;
    int ko  = (n0 + col) % 20;
    int pp  = ((n0 % 20) + col) / 20;
    int gg  = (n0 >> 4) + (col >> 4);
    int c15 = col & 15;
    const float* gDT = wsf + WS_DT;
    uint4*       gF4 = (uint4*)(wsf + WS_F);
    const uint32_t* zp = zsh + pp * 715;
    // 48 quads of r; even quads -> half 0, odd -> half 1; 24 quads x 64 cols
    for (int it = tid; it < 1536; it += 256) {
        int qj = __builtin_amdgcn_readfirstlane(((it >> 6) << 1) | half);  // quad 0..47
        uint32_t fq[4];
        #pragma unroll
        for (int rr = 0; rr < 4; ++rr) {
            int r = 4 * qj + rr;          // wave-uniform scalar
            float fr = 0.f, fi = 0.f;
            if (r < 190) {
                int m = r / 19;
                int n = r - m * 19 - 9;
                int a = n < 0 ? -n : n;
                int lmin = m > a ? m : a;
                switch (lmin) {
                    case 0: fsum<0>(m, n, ko, gDT, zp, fr, fi); break;
                    case 1: fsum<1>(m, n, ko, gDT, zp, fr, fi); break;
                    case 2: fsum<2>(m, n, ko, gDT, zp, fr, fi); break;
                    case 3: fsum<3>(m, n, ko, gDT, zp, fr, fi); break;
                    case 4: fsum<4>(m, n, ko, gDT, zp, fr, fi); break;
                    case 5: fsum<5>(m, n, ko, gDT, zp, fr, fi); break;
                    case 6: fsum<6>(m, n, ko, gDT, zp, fr, fi); break;
                    case 7: fsum<7>(m, n, ko, gDT, zp, fr, fi); break;
                    case 8: fsum<8>(m, n, ko, gDT, zp, fr, fi); break;
                    default: fsum<9>(m, n, ko, gDT, zp, fr, fi); break;
                }
            }
            union { _Float16 h[2]; uint32_t u; } fv;
            fv.h[0] = (_Float16)fr; fv.h[1] = (_Float16)fi;
            fq[rr] = fv.u;
        }
        // chunk = qj>>2, qp = qj&3; dwords 0..3 = r&3 -> one dense 16B store
        gF4[((qj >> 2) * 3200 + gg) * 64 + (qj & 3) * 16 + c15] =
            make_uint4(fq[0], fq[1], fq[2], fq[3]);
    }
}

// ---- k_gemm2: B staged wholly in LDS (one burst), tile-split 2x (v11) ----
extern "C" __global__ void __launch_bounds__(256) k_gemm2(const float* __restrict__ wsf,
                                                           const float* __restrict__ bias,
                                                           float* __restrict__ out) {
    __shared__ __align__(16) _Float16 Bsh[12 * 4 * 64 * 8];   // 48 KB
    int tid = threadIdx.x;
    int h  = blockIdx.x & 1;
    int n0 = (blockIdx.x >> 1) * 64;
    int wave = tid >> 6, lane = tid & 63;
    int g0 = n0 >> 4;
    const half8* gA = (const half8*)(wsf + WS_AP);
    const half8* gB = (const half8*)(wsf + WS_F);
    half8* lB = (half8*)Bsh;

    // ---- stage ALL B for this n0 into LDS: 12 frags/wave, loads batched ----
    half8 stg[12];
    #pragma unroll
    for (int i = 0; i < 12; ++i) {
        int cf = wave * 12 + i;                  // cf = c*4 + f, 0..47
        int c = cf >> 2, f = cf & 3;
        stg[i] = gB[(c * 3200 + g0 + f) * 64 + lane];
    }
    #pragma unroll
    for (int i = 0; i < 12; ++i)
        lB[(wave * 12 + i) * 64 + lane] = stg[i];

    int nt = (h == 0 && wave == 0) ? 4 : 3;
    int t0 = h * 13 + (h == 0 ? (wave == 0 ? 0 : 4 + 3 * (wave - 1)) : 3 * wave);

    f32x4 acc[4][4];
    #pragma unroll
    for (int tt = 0; tt < 4; ++tt)
        #pragma unroll
        for (int f = 0; f < 4; ++f) acc[tt][f] = (f32x4){0.f, 0.f, 0.f, 0.f};

    half8 bufA[2][4];
    #pragma unroll
    for (int tt = 0; tt < 4; ++tt)
        if (tt < nt) bufA[0][tt] = gA[(t0 + tt) * 64 + lane];

    __syncthreads();   // B resident in LDS

    #pragma unroll
    for (int c = 0; c < 12; ++c) {
        const int cur = c & 1, nxt = cur ^ 1;
        if (c < 11) {
            #pragma unroll
            for (int tt = 0; tt < 4; ++tt)
                if (tt < nt) bufA[nxt][tt] = gA[((c + 1) * 28 + t0 + tt) * 64 + lane];
        }
        half8 bB[4];
        #pragma unroll
        for (int f = 0; f < 4; ++f) bB[f] = lB[(c * 4 + f) * 64 + lane];
        #pragma unroll
        for (int tt = 0; tt < 4; ++tt) {
            if (tt < nt) {
                #pragma unroll
                for (int f = 0; f < 4; ++f)
                    acc[tt][f] = __builtin_amdgcn_mfma_f32_16x16x32_f16(bufA[cur][tt], bB[f], acc[tt][f], 0, 0, 0);
            }
        }
    }

    int quad4 = (lane >> 4) << 2, col15 = lane & 15;
    float bo_f[4];
    #pragma unroll
    for (int f = 0; f < 4; ++f) bo_f[f] = bias[((n0 + f * 16 + col15) / 20) % 5];
    #pragma unroll
    for (int tt = 0; tt < 4; ++tt) {
        if (tt < nt) {
            int pqb = (t0 + tt) * 16 + quad4;
            #pragma unroll
            for (int f = 0; f < 4; ++f) {
                int n = n0 + f * 16 + col15;
                float bo = bo_f[f];
                float4 v = make_float4(acc[tt][f].x + bo, acc[tt][f].y + bo,
                                       acc[tt][f].z + bo, acc[tt][f].w + bo);
                *(float4*)(out + n * 400 + pqb) = v;
            }
        }
    }
}

extern "C" void kernel_launch(void* const* d_in, const int* in_sizes, int n_in,
                              void* d_out, int out_size, void* d_ws, size_t ws_size,
                              hipStream_t stream) {
    const float* x    = (const float*)d_in[0];
    const float* kern = (const float*)d_in[1];
    const float* bias = (const float*)d_in[2];
    float* out = (float*)d_out;
    float* wsf = (float*)d_ws;
    k_setup_w    <<<1,    64,  0, stream>>>(wsf);
    k_setup_const<<<3003, 64,  0, stream>>>(wsf, kern);
    k_fhat       <<<1024, 256, 0, stream>>>(x, wsf);
    k_zF         <<<1600, 256, 0, stream>>>(wsf);
    k_gemm2      <<<1600, 256, 0, stream>>>(wsf, bias, out);
}

// Round 10
// 174.334 us; speedup vs baseline: 1.1726x; 1.0270x over previous
//
#include <hip/hip_runtime.h>
#include <math.h>
#include <stdint.h>

// ---------------------------------------------------------------------------
// v13: v12 + k_gemm2 back to grid 800 (h-split removed) while KEEPING the
// whole-slice B LDS burst staging. v11's h-split doubled B stage traffic to
// 76.8 MB (L3-bound ~26-31us); grid 800 stages each 48KB slice exactly once
// (38.4 MB total). Tile mapping = v7's proven t0=wave*7, ntile 7/7/7/4.
// zF (quad-store form) unchanged from v12.
// Pipeline: setup_w -> setup_const -> fhat -> zF -> gemm2.
// ---------------------------------------------------------------------------

typedef _Float16 half8 __attribute__((ext_vector_type(8)));
typedef float    f32x4 __attribute__((ext_vector_type(4)));

// workspace float offsets
#define WS_W    128     // gW [k60][sm55]                 3300
#define WS_Y    17760   // gyhat [o5][s100][i2] float2
#define WS_EM   19776   // gEm [m10][j60] float2
#define WS_TRIG 20992   // 20 dbl sin + 20 dbl cos (ex-gRT region)
#define WS_PACK 21184   // gPack[715] int
#define WS_AP   21952   // A-pack 172032 fp16
#define WS_FH   107968  // gfhat [b512][sm55][i2] float2 = 112640 floats
#define WS_DT   220608  // gDT [p715][k20] = 14300 floats
#define WS_F    234908  // gF 9,830,400 dwords (39.3 MB) B-frag layout

// setup idx ranges (non-overlapping)
#define IX_Y0    3300
#define IX_EM0   4300
#define IX_RT0   4900
#define IX_PACK0 5090
#define IX_AP0   5805
#define IX_DT0   177837   // IX_AP0 + 172032
#define N_SETUP  192137   // + 14300

__device__ __forceinline__ double ipow_d(double x, int e) {
    double r = 1.0;
    for (int i = 0; i < e; ++i) r *= x;
    return r;
}

__device__ double dsmall(int l, int mp, int m, double beta) {
    double fact[20];
    fact[0] = 1.0;
    for (int i = 1; i < 20; ++i) fact[i] = fact[i - 1] * (double)i;
    double cb = cos(0.5 * beta), sb = sin(0.5 * beta);
    double pref = sqrt(fact[l + m] * fact[l - m] * fact[l + mp] * fact[l - mp]);
    int s0 = m - mp; if (s0 < 0) s0 = 0;
    int s1 = l + m;  if (l - mp < s1) s1 = l - mp;
    double tot = 0.0;
    for (int s = s0; s <= s1; ++s) {
        double den = fact[l + m - s] * fact[s] * fact[mp - m + s] * fact[l - mp - s];
        double sgn = ((mp - m + s) & 1) ? -1.0 : 1.0;
        tot += sgn / den * ipow_d(cb, 2 * l + m - mp - 2 * s) * ipow_d(sb, mp - m + 2 * s);
    }
    return pref * tot;
}

extern "C" __global__ void k_setup_w(float* wsf) {
    double* w = (double*)wsf;
    int t = threadIdx.x;
    if (t < 60) {
        double beta = M_PI * (2 * t + 1) / 120.0;
        double sum = 0.0;
        for (int k = 0; k < 30; ++k)
            sum += sin((double)((2 * t + 1) * (2 * k + 1)) * M_PI / 120.0) / (double)(2 * k + 1);
        w[t] = (2.0 / 30.0) * sin(beta) * sum;
    }
    if (t < 20) {   // A-pack trig table: sin/cos(pi*t/10), exact same expr as original
        double ang = M_PI * (double)t / 10.0;
        ((double*)(wsf + WS_TRIG))[t]      = sin(ang);
        ((double*)(wsf + WS_TRIG))[20 + t] = cos(ang);
    }
}

extern "C" __global__ void k_setup_const(float* wsf, const float* __restrict__ kern) {
    const double* w = (const double*)wsf;
    const int tri[11] = {0, 1, 3, 6, 10, 15, 21, 28, 36, 45, 55};
    int idx = blockIdx.x * 64 + threadIdx.x;
    if (idx < IX_Y0) {                      // gW [k][sm]
        int k = idx / 55, smi = idx % 55;
        int l = 0; while (smi >= tri[l + 1]) ++l;
        int m = smi - tri[l];
        double beta = M_PI * (2 * k + 1) / 120.0;
        wsf[WS_W + idx] = (float)(w[k] * dsmall(l, m, 0, beta));
    } else if (idx < IX_EM0) {              // gyhat [o][s][i]
        int i3 = idx - IX_Y0;
        int o = i3 / 200, r5 = i3 % 200;
        int s = r5 / 2, i = r5 % 2;
        int l = 0; while ((l + 1) * (l + 1) <= s) ++l;
        int n = s - l * l - l;
        double dv = dsmall(l, n, 0, M_PI / 160.0);
        const double SC = 1.0 / sqrt(6.0 * 2.0 * 10000.0 / 900.0);
        double ar = 0.0, ai = 0.0;
        for (int g = 0; g < 6; ++g) {
            double kv = (double)kern[i * 30 + o * 6 + g];
            double ang = (double)n * M_PI * (double)g / 3.0;
            ar += kv * cos(ang);
            ai -= kv * sin(ang);
        }
        ((float2*)(wsf + WS_Y))[i3] = make_float2((float)(SC * dv * ar), (float)(SC * dv * ai));
    } else if (idx < IX_RT0) {              // gEm [m][j]
        int t = idx - IX_EM0; int m = t / 60, j = t % 60;
        double a = 2.0 * M_PI * (double)(m * j) / 60.0;
        ((float2*)(wsf + WS_EM))[t] = make_float2((float)cos(a), (float)(-sin(a)));
    } else if (idx < IX_PACK0) {
        // ex-gRT region holds the trig table (written by k_setup_w)
    } else if (idx < IX_AP0) {              // gPack[715]
        int p = idx - IX_PACK0;
        int l = 0, bcur = 0;
        for (;;) { int bs = (l + 1) * (2 * l + 1); if (p < bcur + bs) break; bcur += bs; ++l; }
        int r = p - bcur; int L = 2 * l + 1;
        int m = r / L; int n = r % L - l;
        int smi = tri[l] + m; int sf = l * l + l + n;
        ((int*)(wsf + WS_PACK))[p] = smi * 128 + sf;
    } else if (idx < IX_DT0) {              // A-pack (A-fragment lane order), table lookup
        int ap = idx - IX_AP0;
        int j = ap & 7, lane = (ap >> 3) & 63, tc = ap >> 9;
        int t = tc % 28, c = tc / 28;
        int pq = t * 16 + (lane & 15);
        int kidx = c * 32 + ((lane >> 4) << 3) + j;
        double val = 0.0;
        if (pq < 400 && kidx < 380) {
            int r = kidx >> 1, cpart = kidx & 1;
            int m = r / 19, nn = r % 19, n = nn - 9;
            int p = pq / 20, q = pq % 20;
            int th = ((m * p + n * q) % 20 + 20) % 20;
            double wm = m ? 2.0 : 1.0;
            const double* st = (const double*)(wsf + WS_TRIG);
            val = cpart ? (-wm * st[th]) : (wm * st[20 + th]);
        }
        ((_Float16*)(wsf + WS_AP))[ap] = (_Float16)val;
    } else if (idx < N_SETUP) {             // gDT [p][k] transposed
        int i6 = idx - IX_DT0;
        int p = i6 / 20, k = i6 % 20;
        int l = 0, bcur = 0;
        for (;;) { int bs = (l + 1) * (2 * l + 1); if (p < bcur + bs) break; bcur += bs; ++l; }
        int r = p - bcur; int L = 2 * l + 1;
        int m = r / L; int n = r % L - l;
        double beta = M_PI * (2 * k + 1) / 40.0;
        wsf[WS_DT + i6] = (float)((double)L * dsmall(l, m, n, beta));
    }
}

// ---- fhat: block per (b,i) ----
extern "C" __global__ void __launch_bounds__(256) k_fhat(const float* __restrict__ x,
                                                          float* __restrict__ wsf) {
    __shared__ float  xs[3600];
    __shared__ float2 ems[610];
    __shared__ float2 Y[600];
    int tid = threadIdx.x;
    int bi = blockIdx.x;
    const float4* xp = (const float4*)(x + bi * 3600);
    for (int t = tid; t < 900; t += 256) ((float4*)xs)[t] = xp[t];
    const float2* gEm = (const float2*)(wsf + WS_EM);
    for (int t = tid; t < 600; t += 256) {
        int m = t / 60, j = t - m * 60;
        ems[m * 61 + j] = gEm[t];
    }
    __syncthreads();
    for (int it = tid; it < 600; it += 256) {
        int k = it / 10, m = it - k * 10;
        const float*  row = xs + k * 60;
        const float2* em  = ems + m * 61;
        float ar = 0.f, ai = 0.f;
        #pragma unroll 12
        for (int j = 0; j < 60; ++j) {
            float xv = row[j];
            float2 e = em[j];
            ar += xv * e.x; ai += xv * e.y;
        }
        Y[it] = make_float2(ar, ai);
    }
    __syncthreads();
    if (tid < 55) {
        int smi = tid;
        const int tri[11] = {0, 1, 3, 6, 10, 15, 21, 28, 36, 45, 55};
        int l = 0; while (smi >= tri[l + 1]) ++l;
        int m = smi - tri[l];
        const float* gW = wsf + WS_W;
        float ar = 0.f, ai = 0.f;
        for (int kk = 0; kk < 60; ++kk) {
            float wv = gW[kk * 55 + smi];
            float2 y = Y[kk * 10 + m];
            ar += wv * y.x; ai += wv * y.y;
        }
        int b = bi >> 1, i = bi & 1;
        ((float2*)(wsf + WS_FH))[b * 110 + smi * 2 + i] = make_float2(ar, ai);
    }
}

// unrolled F-sum for compile-time lmin L: steps l = L..9, straight-line,
// all loads independent -> full MLP. z is fp16-packed in LDS.
template<int L>
__device__ __forceinline__ void fsum(int m, int n, int ko, const float* __restrict__ gDT,
                                     const uint32_t* zp, float& fr, float& fi) {
    const int baseL[10] = {0, 1, 7, 22, 50, 95, 161, 252, 372, 525};
    float dv[10 - L];
    uint32_t zv[10 - L];
    #pragma unroll
    for (int l = L; l < 10; ++l) {
        int p = baseL[l] + m * (2 * l + 1) + n + l;
        dv[l - L] = gDT[p * 20 + ko];
        zv[l - L] = zp[p];
    }
    #pragma unroll
    for (int l = L; l < 10; ++l) {
        union { uint32_t u; _Float16 h[2]; } zc; zc.u = zv[l - L];
        fr += dv[l - L] * (float)zc.h[0];
        fi += dv[l - L] * (float)zc.h[1];
    }
}

// ---- k_zF: z + F, write gF in B-frag layout (v12 quad-store form) ----
extern "C" __global__ void __launch_bounds__(256) k_zF(float* __restrict__ wsf) {
    __shared__ uint32_t zsh[2860];    // z [pp4][p715] fp16-packed (11.4 KB)
    __shared__ float4 fbl4[110];
    __shared__ float4 yol4[500];
    int tid = threadIdx.x;
    int half = blockIdx.x & 1;
    int nb   = blockIdx.x >> 1;
    int n0 = nb * 64;
    int PO0 = n0 / 20;
    int bf = PO0 / 5;

    const float4* gfh4 = (const float4*)(wsf + WS_FH);
    for (int t = tid; t < 110; t += 256) {
        int bsel = t / 55, i55 = t - bsel * 55;
        int b = bf + bsel;
        fbl4[t] = (b < 512) ? gfh4[b * 55 + i55] : make_float4(0.f, 0.f, 0.f, 0.f);
    }
    for (int t = tid; t < 500; t += 256) yol4[t] = ((const float4*)(wsf + WS_Y))[t];
    __syncthreads();
    const int* gPack = (const int*)(wsf + WS_PACK);
    for (int pp = 0; pp < 4; ++pp) {
        int po = PO0 + pp;
        int b_loc = po / 5 - bf, o = po % 5;
        for (int p = tid; p < 715; p += 256) {
            int pk = gPack[p];
            int smi = pk >> 7, sf = pk & 127;
            float4 f = fbl4[b_loc * 55 + smi];
            float4 y = yol4[o * 100 + sf];
            float zr = f.x * y.x + f.y * y.y + f.z * y.z + f.w * y.w;
            float zi = f.y * y.x - f.x * y.y + f.w * y.z - f.z * y.w;
            union { _Float16 h[2]; uint32_t u; } cv;
            cv.h[0] = (_Float16)zr; cv.h[1] = (_Float16)zi;
            zsh[pp * 715 + p] = cv.u;
        }
    }
    __syncthreads();

    int col = tid & 63;
    int ko  = (n0 + col) % 20;
    int pp  = ((n0 % 20) + col) / 20;
    int gg  = (n0 >> 4) + (col >> 4);
    int c15 = col & 15;
    const float* gDT = wsf + WS_DT;
    uint4*       gF4 = (uint4*)(wsf + WS_F);
    const uint32_t* zp = zsh + pp * 715;
    // 48 quads of r; even quads -> half 0, odd -> half 1; 24 quads x 64 cols
    for (int it = tid; it < 1536; it += 256) {
        int qj = __builtin_amdgcn_readfirstlane(((it >> 6) << 1) | half);  // quad 0..47
        uint32_t fq[4];
        #pragma unroll
        for (int rr = 0; rr < 4; ++rr) {
            int r = 4 * qj + rr;          // wave-uniform scalar
            float fr = 0.f, fi = 0.f;
            if (r < 190) {
                int m = r / 19;
                int n = r - m * 19 - 9;
                int a = n < 0 ? -n : n;
                int lmin = m > a ? m : a;
                switch (lmin) {
                    case 0: fsum<0>(m, n, ko, gDT, zp, fr, fi); break;
                    case 1: fsum<1>(m, n, ko, gDT, zp, fr, fi); break;
                    case 2: fsum<2>(m, n, ko, gDT, zp, fr, fi); break;
                    case 3: fsum<3>(m, n, ko, gDT, zp, fr, fi); break;
                    case 4: fsum<4>(m, n, ko, gDT, zp, fr, fi); break;
                    case 5: fsum<5>(m, n, ko, gDT, zp, fr, fi); break;
                    case 6: fsum<6>(m, n, ko, gDT, zp, fr, fi); break;
                    case 7: fsum<7>(m, n, ko, gDT, zp, fr, fi); break;
                    case 8: fsum<8>(m, n, ko, gDT, zp, fr, fi); break;
                    default: fsum<9>(m, n, ko, gDT, zp, fr, fi); break;
                }
            }
            union { _Float16 h[2]; uint32_t u; } fv;
            fv.h[0] = (_Float16)fr; fv.h[1] = (_Float16)fi;
            fq[rr] = fv.u;
        }
        // chunk = qj>>2, qp = qj&3; dwords 0..3 = r&3 -> one dense 16B store
        gF4[((qj >> 2) * 3200 + gg) * 64 + (qj & 3) * 16 + c15] =
            make_uint4(fq[0], fq[1], fq[2], fq[3]);
    }
}

// ---- k_gemm2: grid 800, whole 48KB B-slice LDS burst, v7 tile mapping ----
extern "C" __global__ void __launch_bounds__(256) k_gemm2(const float* __restrict__ wsf,
                                                           const float* __restrict__ bias,
                                                           float* __restrict__ out) {
    __shared__ __align__(16) _Float16 Bsh[12 * 4 * 64 * 8];   // 48 KB
    int tid = threadIdx.x;
    int n0 = blockIdx.x * 64;
    int wave = tid >> 6, lane = tid & 63;
    int g0 = n0 >> 4;
    const half8* gA = (const half8*)(wsf + WS_AP);
    const half8* gB = (const half8*)(wsf + WS_F);
    half8* lB = (half8*)Bsh;

    // ---- stage ALL B for this n0 into LDS: 12 frags/wave, loads batched ----
    half8 stg[12];
    #pragma unroll
    for (int i = 0; i < 12; ++i) {
        int cf = wave * 12 + i;                  // cf = c*4 + f, 0..47
        int c = cf >> 2, f = cf & 3;
        stg[i] = gB[(c * 3200 + g0 + f) * 64 + lane];
    }
    #pragma unroll
    for (int i = 0; i < 12; ++i)
        lB[(wave * 12 + i) * 64 + lane] = stg[i];

    int t0 = wave * 7;
    int ntile = (wave < 3) ? 7 : 4;          // tiles 21..24 real; 25..27 pad

    f32x4 acc[7][4];
    #pragma unroll
    for (int tt = 0; tt < 7; ++tt)
        #pragma unroll
        for (int f = 0; f < 4; ++f) acc[tt][f] = (f32x4){0.f, 0.f, 0.f, 0.f};

    half8 bufA[2][7];
    #pragma unroll
    for (int tt = 0; tt < 7; ++tt)
        if (tt < ntile) bufA[0][tt] = gA[(t0 + tt) * 64 + lane];

    __syncthreads();   // B resident in LDS

    #pragma unroll
    for (int c = 0; c < 12; ++c) {
        const int cur = c & 1, nxt = cur ^ 1;
        if (c < 11) {
            #pragma unroll
            for (int tt = 0; tt < 7; ++tt)
                if (tt < ntile) bufA[nxt][tt] = gA[((c + 1) * 28 + t0 + tt) * 64 + lane];
        }
        half8 bB[4];
        #pragma unroll
        for (int f = 0; f < 4; ++f) bB[f] = lB[(c * 4 + f) * 64 + lane];
        #pragma unroll
        for (int tt = 0; tt < 7; ++tt) {
            if (tt < ntile) {
                #pragma unroll
                for (int f = 0; f < 4; ++f)
                    acc[tt][f] = __builtin_amdgcn_mfma_f32_16x16x32_f16(bufA[cur][tt], bB[f], acc[tt][f], 0, 0, 0);
            }
        }
    }

    int quad4 = (lane >> 4) << 2, col15 = lane & 15;
    float bo_f[4];
    #pragma unroll
    for (int f = 0; f < 4; ++f) bo_f[f] = bias[((n0 + f * 16 + col15) / 20) % 5];
    #pragma unroll
    for (int tt = 0; tt < 7; ++tt) {
        if (tt < ntile) {
            int pqb = (t0 + tt) * 16 + quad4;
            #pragma unroll
            for (int f = 0; f < 4; ++f) {
                int n = n0 + f * 16 + col15;
                float bo = bo_f[f];
                float4 v = make_float4(acc[tt][f].x + bo, acc[tt][f].y + bo,
                                       acc[tt][f].z + bo, acc[tt][f].w + bo);
                *(float4*)(out + n * 400 + pqb) = v;
            }
        }
    }
}

extern "C" void kernel_launch(void* const* d_in, const int* in_sizes, int n_in,
                              void* d_out, int out_size, void* d_ws, size_t ws_size,
                              hipStream_t stream) {
    const float* x    = (const float*)d_in[0];
    const float* kern = (const float*)d_in[1];
    const float* bias = (const float*)d_in[2];
    float* out = (float*)d_out;
    float* wsf = (float*)d_ws;
    k_setup_w    <<<1,    64,  0, stream>>>(wsf);
    k_setup_const<<<3003, 64,  0, stream>>>(wsf, kern);
    k_fhat       <<<1024, 256, 0, stream>>>(x, wsf);
    k_zF         <<<1600, 256, 0, stream>>>(wsf);
    k_gemm2      <<<800,  256, 0, stream>>>(wsf, bias, out);
}